// Round 5
// baseline (403.638 us; speedup 1.0000x reference)
//
#include <hip/hip_runtime.h>
#include <math.h>

#define NN 4096

typedef __bf16 bf16;
typedef __attribute__((ext_vector_type(4))) __bf16 bf16x4;
typedef __attribute__((ext_vector_type(8))) __bf16 bf16x8;
typedef __attribute__((ext_vector_type(4))) float f32x4;

__device__ __forceinline__ void gld16(const void* g, void* l) {
  __builtin_amdgcn_global_load_lds((const __attribute__((address_space(1))) void*)g,
                                   (__attribute__((address_space(3))) void*)l, 16, 0, 0);
}

// ---------- block reduction helpers (blockDim.x == 256) ----------

__device__ __forceinline__ double blockSumD(double v) {
  __shared__ double w[4];
  #pragma unroll
  for (int o = 32; o > 0; o >>= 1) v += __shfl_down(v, o, 64);
  __syncthreads();
  if ((threadIdx.x & 63) == 0) w[threadIdx.x >> 6] = v;
  __syncthreads();
  return w[0] + w[1] + w[2] + w[3];
}

__device__ __forceinline__ float blockMaxF(float v) {
  __shared__ float w[4];
  #pragma unroll
  for (int o = 32; o > 0; o >>= 1) v = fmaxf(v, __shfl_down(v, o, 64));
  __syncthreads();
  if ((threadIdx.x & 63) == 0) w[threadIdx.x >> 6] = v;
  __syncthreads();
  return fmaxf(fmaxf(w[0], w[1]), fmaxf(w[2], w[3]));
}

// ---------- kernel 1: row softmax of x,y -> bf16, exact row sum-of-squares; zero out[0] ----------

__global__ void softmax_rows(const float* __restrict__ x, const float* __restrict__ y,
                             bf16* __restrict__ xh, bf16* __restrict__ yh,
                             float* __restrict__ rowsq, float* __restrict__ out) {
  int row = blockIdx.x;
  int t = threadIdx.x;
  if (row == 0 && t == 0) out[0] = 0.0f;  // init for cost atomics in pi_cost_fused
  int r = (row < NN) ? row : row - NN;
  const f32x4* __restrict__ src = (const f32x4*)(((row < NN) ? x : y) + (size_t)r * NN);
  bf16x4* __restrict__ dst = (bf16x4*)(((row < NN) ? xh : yh) + (size_t)r * NN);

  f32x4 v[4];
  float m = -3.402823466e38f;
  #pragma unroll
  for (int j = 0; j < 4; ++j) {
    v[j] = src[t + 256 * j];
    m = fmaxf(fmaxf(fmaxf(m, v[j].x), fmaxf(v[j].y, v[j].z)), v[j].w);
  }
  float M = blockMaxF(m);

  float s = 0.0f;
  #pragma unroll
  for (int j = 0; j < 4; ++j) {
    v[j].x = __expf(v[j].x - M); v[j].y = __expf(v[j].y - M);
    v[j].z = __expf(v[j].z - M); v[j].w = __expf(v[j].w - M);
    s += (v[j].x + v[j].y) + (v[j].z + v[j].w);
  }
  double S = blockSumD((double)s);
  float inv = (float)(1.0 / S);

  float q = 0.0f;
  #pragma unroll
  for (int j = 0; j < 4; ++j) {
    f32x4 p = v[j] * inv;
    bf16x4 h;
    h.x = (bf16)p.x; h.y = (bf16)p.y; h.z = (bf16)p.z; h.w = (bf16)p.w;
    dst[t + 256 * j] = h;
    q += (p.x * p.x + p.y * p.y) + (p.z * p.z + p.w * p.w);
  }
  double Q = blockSumD((double)q);
  if (t == 0) rowsq[row] = (float)Q;
}

// ---------- kernel 2: C = x2 + y2 - 2 * sx . sy^T  (bf16 MFMA) + fused column exp-sums ----------
// 128x128 tile, BK=64, 4 waves, 4x4 16x16x32 MFMA tiles/wave. XOR-swizzled LDS (0 conflicts).
// Epilogue also emits colpart[by][col] = sum over the block's 128 rows of exp(-10*C).
// NOTE: 88 VGPR + 64 AGPR = 152 unified regs -> 3 blocks/CU. Do NOT assume 4 (round-4 lesson).

__global__ __launch_bounds__(256) void gemm_bt(const bf16* __restrict__ A,
                                               const bf16* __restrict__ B,
                                               const float* __restrict__ rowsq,
                                               float* __restrict__ C,
                                               float* __restrict__ colpart) {
  __shared__ __align__(16) bf16 As[128 * 64];
  __shared__ __align__(16) bf16 Bs[128 * 64];
  __shared__ float lsc[2][128];
  int t = threadIdx.x;
  int i0 = blockIdx.y * 128;
  int j0 = blockIdx.x * 128;
  int w = t >> 6, l = t & 63;
  int mrow = (w >> 1) * 64, ncol = (w & 1) * 64;
  int lr = l & 15, lq = l >> 4;

  f32x4 acc[4][4] = {};

  for (int kc = 0; kc < NN; kc += 64) {
    __syncthreads();
    #pragma unroll
    for (int q = 0; q < 4; ++q) {
      int c = t + 256 * q;              // LDS chunk index 0..1023
      int row = c >> 3;
      int jg = (c & 7) ^ (row & 7);     // swizzled source chunk within the row
      gld16(A + (size_t)(i0 + row) * NN + kc + jg * 8, (char*)As + c * 16);
    }
    #pragma unroll
    for (int q = 0; q < 4; ++q) {
      int c = t + 256 * q;
      int row = c >> 3;
      int jg = (c & 7) ^ (row & 7);
      gld16(B + (size_t)(j0 + row) * NN + kc + jg * 8, (char*)Bs + c * 16);
    }
    __syncthreads();

    #pragma unroll
    for (int s = 0; s < 2; ++s) {
      bf16x8 af[4], bg[4];
      #pragma unroll
      for (int i = 0; i < 4; ++i) {
        int ra = mrow + 16 * i + lr;
        int ja = (s * 4 + lq) ^ (ra & 7);
        af[i] = *(const bf16x8*)((const char*)As + (ra * 8 + ja) * 16);
        int rb = ncol + 16 * i + lr;
        int jb = (s * 4 + lq) ^ (rb & 7);
        bg[i] = *(const bf16x8*)((const char*)Bs + (rb * 8 + jb) * 16);
      }
      #pragma unroll
      for (int i = 0; i < 4; ++i)
        #pragma unroll
        for (int jj = 0; jj < 4; ++jj)
          acc[i][jj] = __builtin_amdgcn_mfma_f32_16x16x32_bf16(af[i], bg[jj], acc[i][jj], 0, 0, 0);
    }
  }

  float y2v[4], ec[4] = {0.f, 0.f, 0.f, 0.f};
  #pragma unroll
  for (int jj = 0; jj < 4; ++jj) y2v[jj] = rowsq[NN + j0 + ncol + 16 * jj + lr];
  #pragma unroll
  for (int i = 0; i < 4; ++i) {
    #pragma unroll
    for (int r = 0; r < 4; ++r) {
      int grow = i0 + mrow + 16 * i + lq * 4 + r;
      float x2 = rowsq[grow];
      size_t rowoff = (size_t)grow * NN + j0 + ncol;
      #pragma unroll
      for (int jj = 0; jj < 4; ++jj) {
        float cv = x2 + y2v[jj] - 2.0f * acc[i][jj][r];
        C[rowoff + 16 * jj + lr] = cv;
        ec[jj] += __expf(-10.0f * cv);
      }
    }
  }
  // reduce over lq (lanes lr, lr+16, lr+32, lr+48 hold the same columns)
  #pragma unroll
  for (int jj = 0; jj < 4; ++jj) {
    ec[jj] += __shfl_xor(ec[jj], 16, 64);
    ec[jj] += __shfl_xor(ec[jj], 32, 64);
  }
  if (lq == 0) {
    #pragma unroll
    for (int jj = 0; jj < 4; ++jj) lsc[w >> 1][ncol + 16 * jj + lr] = ec[jj];
  }
  __syncthreads();
  if (t < 128) colpart[(size_t)blockIdx.y * NN + j0 + t] = lsc[0][t] + lsc[1][t];
}

// ---------- kernel 3: fused s_j + pi + cost ----------
// Block (bx,by) covers cols [bx*128,+128) x rows [by*128,+128).
// Threads t<128 compute s_j for the tile's columns from colpart (f64 sum + log),
// then all 256 threads stream the tile: pi = exp(-10*C + s_j), cost fma.
// Per-block cost -> f64 block reduce -> one f32 atomicAdd into out[0].

__global__ void pi_cost_fused(const float* __restrict__ Cm, const float* __restrict__ colpart,
                              float* __restrict__ pi, float* __restrict__ out) {
  __shared__ float sdl[128];
  int t = threadIdx.x;
  int j0 = blockIdx.x * 128;
  int r0 = blockIdx.y * 128;
  if (t < 128) {
    double s = 0.0;
    #pragma unroll
    for (int ch = 0; ch < 32; ++ch) s += (double)colpart[(size_t)ch * NN + j0 + t];
    sdl[t] = (float)(-8.317725207557924 - log(s));  // log_nu - log(S_j)
  }
  __syncthreads();

  int col = t & 127, rh = t >> 7;
  float sj = sdl[col];
  float facc = 0.0f;
  #pragma unroll 8
  for (int rr = 0; rr < 64; ++rr) {
    int row = r0 + rr * 2 + rh;
    size_t idx = (size_t)row * NN + j0 + col;
    float c = Cm[idx];
    float p = __expf(fmaf(-10.0f, c, sj));
    pi[idx] = p;
    facc = fmaf(p, c, facc);
  }
  double total = blockSumD((double)facc);
  if (t == 0) atomicAdd(out, (float)total);
}

// ---------- launch ----------

extern "C" void kernel_launch(void* const* d_in, const int* in_sizes, int n_in,
                              void* d_out, int out_size, void* d_ws, size_t ws_size,
                              hipStream_t stream) {
  const float* x = (const float*)d_in[0];
  const float* y = (const float*)d_in[1];
  float* out = (float*)d_out;
  float* pi = out + 1;                          // [NN*NN] floats
  float* Cm = out + 1 + (size_t)NN * NN;        // [NN*NN] floats

  char* ws = (char*)d_ws;
  bf16* xh = (bf16*)ws;                                          // 32 MiB
  bf16* yh = xh + (size_t)NN * NN;                               // 32 MiB
  size_t off = (size_t)NN * NN * 2 * 2;
  float* rowsq = (float*)(ws + off);       off += 2 * NN * 4;    // 32 KiB
  float* colpart = (float*)(ws + off);     off += 32 * NN * 4;   // 512 KiB

  hipLaunchKernelGGL(softmax_rows, dim3(2 * NN), dim3(256), 0, stream, x, y, xh, yh, rowsq, out);
  hipLaunchKernelGGL(gemm_bt, dim3(32, 32), dim3(256), 0, stream, xh, yh, rowsq, Cm, colpart);
  hipLaunchKernelGGL(pi_cost_fused, dim3(32, 32), dim3(256), 0, stream, Cm, colpart, pi, out);
}